// Round 12
// baseline (342.696 us; speedup 1.0000x reference)
//
#include <hip/hip_runtime.h>
#include <hip/hip_bf16.h>

typedef __hip_bfloat16 bf16;
typedef __attribute__((ext_vector_type(8))) short bf16x8;
typedef __attribute__((ext_vector_type(4))) float f32x4;

constexpr int NB    = 64;
constexpr int EE    = 512;
constexpr int RPOS  = 27 * 27;       // 729
constexpr int ROWS  = NB * 14 * 14;  // 12544

#define RMS_EPS 1e-6f
#define GAMMA_LOG2 (-0.00144344319f)   // log2(0.999)

__device__ __forceinline__ void  stf(float* p, float v) { *p = v; }
__device__ __forceinline__ void  stf(bf16* p, float v)  { *p = __float2bfloat16(v); }

__device__ __forceinline__ void gload_lds16(const bf16* g, bf16* l) {
    __builtin_amdgcn_global_load_lds(
        (const __attribute__((address_space(1))) void*)g,
        (__attribute__((address_space(3))) void*)l, 16, 0, 0);
}

#define VMCNT(n) asm volatile("s_waitcnt vmcnt(" #n ")" ::: "memory")

// ---------------------------------------------------------------------------
// One-shot prep: 7 weight transposes (fp32 [R][C] -> bf16 [C][R]), bias
// concat, x -> bf16.
__global__ __launch_bounds__(256) void k_prep(const float* __restrict__ Wu,
                                              const float* __restrict__ Wv,
                                              const float* __restrict__ Wo,
                                              const float* __restrict__ w1,
                                              const float* __restrict__ w2,
                                              const float* __restrict__ w3,
                                              const float* __restrict__ wOut,
                                              const float* __restrict__ bu,
                                              const float* __restrict__ bv,
                                              const float* __restrict__ x,
                                              bf16* __restrict__ WuvT,
                                              bf16* __restrict__ WoT,
                                              bf16* __restrict__ w1T,
                                              bf16* __restrict__ w2T,
                                              bf16* __restrict__ w3T,
                                              bf16* __restrict__ wOutT,
                                              float* __restrict__ biasUv,
                                              bf16* __restrict__ xb) {
    __shared__ float t[32][33];
    const int tid = threadIdx.x;
    int b = blockIdx.x;

    const float* src = nullptr; bf16* dst = nullptr; int R = 0, C = 0, nbx = 0;
    if (b < 512)        { src = Wu;   dst = WuvT;                      R = 512;  C = 1024; nbx = 32; }
    else if (b < 1024)  { b -= 512;   src = Wv; dst = WuvT + (size_t)1024 * 512; R = 512; C = 1024; nbx = 32; }
    else if (b < 1536)  { b -= 1024;  src = Wo;   dst = WoT;           R = 1024; C = 512;  nbx = 16; }
    else if (b < 1792)  { b -= 1536;  src = w1;   dst = w1T;           R = 512;  C = 512;  nbx = 16; }
    else if (b < 2048)  { b -= 1792;  src = w2;   dst = w2T;           R = 512;  C = 512;  nbx = 16; }
    else if (b < 2304)  { b -= 2048;  src = w3;   dst = w3T;           R = 512;  C = 512;  nbx = 16; }
    else if (b < 2816)  { b -= 2304;  src = wOut; dst = wOutT;         R = 512;  C = 1024; nbx = 32; }
    else if (b < 2824) {               // bias concat
        int c = (b - 2816) * 256 + tid;
        if (c < 2048) biasUv[c] = (c < 1024) ? bu[c] : bv[c - 1024];
        return;
    } else {                           // x -> bf16
        int i = (b - 2824) * 256 + tid;
        float4 v = *(const float4*)&x[(size_t)i * 4];
        bf16* d = &xb[(size_t)i * 4];
        d[0] = __float2bfloat16(v.x);
        d[1] = __float2bfloat16(v.y);
        d[2] = __float2bfloat16(v.z);
        d[3] = __float2bfloat16(v.w);
        return;
    }
    int bx = (b % nbx) * 32;
    int by = (b / nbx) * 32;
    int tx = tid & 31, ty = tid >> 5;
    #pragma unroll
    for (int i = 0; i < 4; ++i)
        t[ty + i * 8][tx] = src[(size_t)(by + ty + i * 8) * C + bx + tx];
    __syncthreads();
    #pragma unroll
    for (int i = 0; i < 4; ++i)
        dst[(size_t)(bx + ty + i * 8) * R + by + tx] = __float2bfloat16(t[tx][ty + i * 8]);
}

// ---------------------------------------------------------------------------
// Device-scope grid barrier (single-use counter, zeroed by hipMemsetAsync
// before launch). Safe: grid (192) <= CU count, kernel runs alone.
__device__ __forceinline__ void gbar(int* bar, int nb) {
    __syncthreads();
    __threadfence();
    if (threadIdx.x == 0) {
        if (atomicAdd(bar, 1) + 1 < nb) {
            while (atomicAdd(bar, 0) < nb) __builtin_amdgcn_s_sleep(2);
        }
    }
    __syncthreads();
    __threadfence();
}

// RPE-layer GEMM body (64x64 tile, BK=32, 4 waves).
// Identity: relu(rmsnorm(x)) @ W = s_row * (relu(x) @ W), s_row > 0.
template <int SCALE_IN, int EPI>
__device__ __forceinline__ void dev_rpe_gemm(const bf16* __restrict__ A,
                                             const bf16* __restrict__ Bt,
                                             const float* __restrict__ bias,
                                             const float* __restrict__ pIn,
                                             float* __restrict__ pOut,
                                             bf16* __restrict__ out,
                                             int bx, int by, int M, int N, int K,
                                             bf16* As, bf16* Bs) {
    const int tid = threadIdx.x;
    const int m0 = by * 64;
    const int n0 = bx * 64;
    const int lane = tid & 63;
    const int w = tid >> 6;
    const int lr = lane & 15;
    const int lk = (lane >> 4) * 8;

    f32x4 acc[4] = {};
    const int row = tid >> 2;
    const int seg = (tid & 3) * 8;

    for (int k0 = 0; k0 < K; k0 += 32) {
        gload_lds16(&A[(size_t)(m0 + row) * K + k0 + seg], &As[tid * 8]);
        gload_lds16(&Bt[(size_t)(n0 + row) * K + k0 + seg], &Bs[tid * 8]);
        __syncthreads();
        bf16x8 af = *(const bf16x8*)&As[(w * 16 + lr) * 32 + lk];
        #pragma unroll
        for (int j = 0; j < 4; ++j) {
            bf16x8 bf = *(const bf16x8*)&Bs[(j * 16 + lr) * 32 + lk];
            acc[j] = __builtin_amdgcn_mfma_f32_16x16x32_bf16(af, bf, acc[j], 0, 0, 0);
        }
        __syncthreads();
    }

    const int crow = (lane >> 4) * 4;
    const int ccol = lane & 15;
    float sc[4];
    #pragma unroll
    for (int r = 0; r < 4; ++r) {
        sc[r] = 1.0f;
        if (SCALE_IN) {
            int gr = m0 + w * 16 + crow + r;
            if (gr < M) {
                const float* pp = &pIn[(size_t)gr * 8];
                float s8 = pp[0] + pp[1] + pp[2] + pp[3] + pp[4] + pp[5] + pp[6] + pp[7];
                sc[r] = rsqrtf(s8 * (1.0f / 512.0f) + RMS_EPS);
            }
        }
    }
    float rowsq[4] = {0.f, 0.f, 0.f, 0.f};
    #pragma unroll
    for (int j = 0; j < 4; ++j) {
        int gc = n0 + j * 16 + ccol;
        float bb = bias[gc];
        #pragma unroll
        for (int r = 0; r < 4; ++r) {
            int gr = m0 + w * 16 + crow + r;
            float val = acc[j][r] * sc[r] + bb;
            if (EPI == 0) {
                rowsq[r] += val * val;
                if (gr < M) out[(size_t)gr * N + gc] = __float2bfloat16(fmaxf(val, 0.0f));
            } else {
                if (gr < M) {
                    int i = gr / 27, jj = gr % 27;
                    float decay = exp2f((float)(abs(i - 13) + abs(jj - 13)) * GAMMA_LOG2);
                    out[(size_t)gr * N + gc] = __float2bfloat16(val * decay);
                }
            }
        }
    }
    if (EPI == 0) {
        #pragma unroll
        for (int r = 0; r < 4; ++r) {
            #pragma unroll
            for (int m = 1; m < 16; m <<= 1) rowsq[r] += __shfl_xor(rowsq[r], m, 64);
        }
        if ((lane & 15) == 0) {
            #pragma unroll
            for (int r = 0; r < 4; ++r) {
                int gr = m0 + w * 16 + crow + r;
                if (gr < M) pOut[(size_t)gr * 8 + bx] = rowsq[r];
            }
        }
    }
}

// Persistent RPE chain: pos+norm, 3 hidden layers, final decay layer — one
// dispatch, device-barrier between phases. Grid = 192 blocks x 256 thr.
__global__ __launch_bounds__(256) void k_rpe_all(const float* __restrict__ rpw,
                                                 const float* __restrict__ rpb,
                                                 const bf16* __restrict__ w1T,
                                                 const float* __restrict__ b1,
                                                 const bf16* __restrict__ w2T,
                                                 const float* __restrict__ b2,
                                                 const bf16* __restrict__ w3T,
                                                 const float* __restrict__ b3,
                                                 const bf16* __restrict__ wOutT,
                                                 const float* __restrict__ bOut,
                                                 bf16* __restrict__ rnA,
                                                 bf16* __restrict__ rnB,
                                                 float* __restrict__ p1,
                                                 float* __restrict__ p2,
                                                 float* __restrict__ p3,
                                                 bf16* __restrict__ Ab,
                                                 int* __restrict__ bar) {
    __shared__ bf16 As[64 * 32];
    __shared__ bf16 Bs[64 * 32];
    __shared__ float ps[4];
    const int nb = gridDim.x;   // 192
    const int tid = threadIdx.x;

    // --- phase 0: r0 = ii*w0+jj*w1+b; rnA = bf16(relu(rmsnorm(r0))) ---
    for (int p = blockIdx.x; p < RPOS; p += nb) {
        float ii = (float)(p / 27 - 13);
        float jj = (float)(p % 27 - 13);
        int c0 = tid, c1 = tid + 256;
        float v0 = ii * rpw[c0] + jj * rpw[512 + c0] + rpb[c0];
        float v1 = ii * rpw[c1] + jj * rpw[512 + c1] + rpb[c1];
        float s = v0 * v0 + v1 * v1;
        #pragma unroll
        for (int off = 32; off; off >>= 1) s += __shfl_down(s, off, 64);
        if ((tid & 63) == 0) ps[tid >> 6] = s;
        __syncthreads();
        float tot = ps[0] + ps[1] + ps[2] + ps[3];
        float scale = rsqrtf(tot * (1.0f / 512.0f) + RMS_EPS);
        rnA[(size_t)p * 512 + c0] = __float2bfloat16(fmaxf(v0 * scale, 0.0f));
        rnA[(size_t)p * 512 + c1] = __float2bfloat16(fmaxf(v1 * scale, 0.0f));
        __syncthreads();
    }
    gbar(bar + 0, nb);
    // --- phase 1: L1 (96 blocks) ---
    if (blockIdx.x < 96)
        dev_rpe_gemm<0, 0>(rnA, w1T, b1, nullptr, p1, rnB,
                           blockIdx.x & 7, blockIdx.x >> 3, RPOS, 512, 512, As, Bs);
    gbar(bar + 1, nb);
    // --- phase 2: L2 ---
    if (blockIdx.x < 96)
        dev_rpe_gemm<1, 0>(rnB, w2T, b2, p1, p2, rnA,
                           blockIdx.x & 7, blockIdx.x >> 3, RPOS, 512, 512, As, Bs);
    gbar(bar + 2, nb);
    // --- phase 3: L3 ---
    if (blockIdx.x < 96)
        dev_rpe_gemm<1, 0>(rnA, w3T, b3, p2, p3, rnB,
                           blockIdx.x & 7, blockIdx.x >> 3, RPOS, 512, 512, As, Bs);
    gbar(bar + 3, nb);
    // --- phase 4: final layer + decay (192 blocks) ---
    dev_rpe_gemm<1, 2>(rnB, wOutT, bOut, p3, nullptr, Ab,
                       blockIdx.x & 15, blockIdx.x >> 4, RPOS, 1024, 512, As, Bs);
}

// ---------------------------------------------------------------------------
// m97-structure 128x128 MFMA GEMM (out GEMM; ~3 blocks/CU).
template <int EPI, typename TO>
__global__ __launch_bounds__(256) void k_mgemm(const bf16* __restrict__ A, int lda,
                                               const bf16* __restrict__ Bt,
                                               const float* __restrict__ bias,
                                               TO* __restrict__ out, int ldo,
                                               int M, int N, int K) {
    __shared__ bf16 As[128 * 32];
    __shared__ bf16 Bs[128 * 32];
    const int tid = threadIdx.x;
    const int m0 = blockIdx.y * 128;
    const int n0 = blockIdx.x * 128;
    const int lane = tid & 63;
    const int w = tid >> 6;
    const int wr = (w >> 1) * 64;
    const int wc = (w & 1) * 64;
    const int lr = lane & 15;
    const int lk = (lane >> 4) * 8;

    f32x4 acc[4][4] = {};

    for (int k0 = 0; k0 < K; k0 += 32) {
        #pragma unroll
        for (int t = 0; t < 2; ++t) {
            int flat = t * 256 + tid;
            int row = flat >> 2;
            int seg = (flat & 3) * 8;
            gload_lds16(&A[(size_t)(m0 + row) * lda + k0 + seg], &As[flat * 8]);
            gload_lds16(&Bt[(size_t)(n0 + row) * K + k0 + seg], &Bs[flat * 8]);
        }
        __syncthreads();
        bf16x8 af[4], bf[4];
        #pragma unroll
        for (int i = 0; i < 4; ++i) {
            af[i] = *(const bf16x8*)&As[(wr + i * 16 + lr) * 32 + lk];
            bf[i] = *(const bf16x8*)&Bs[(wc + i * 16 + lr) * 32 + lk];
        }
        #pragma unroll
        for (int i = 0; i < 4; ++i)
            #pragma unroll
            for (int j = 0; j < 4; ++j)
                acc[i][j] = __builtin_amdgcn_mfma_f32_16x16x32_bf16(af[i], bf[j], acc[i][j], 0, 0, 0);
        __syncthreads();
    }

    const int crow = (lane >> 4) * 4;
    const int ccol = lane & 15;
    #pragma unroll
    for (int i = 0; i < 4; ++i)
        #pragma unroll
        for (int j = 0; j < 4; ++j) {
            int gc = n0 + wc + j * 16 + ccol;
            float bb = bias[gc];
            #pragma unroll
            for (int r = 0; r < 4; ++r) {
                int gr = m0 + wr + i * 16 + crow + r;
                float val = acc[i][j][r] + bb;
                if (EPI == 1) val = val / (1.0f + expf(-val));
                stf(&out[(size_t)gr * ldo + gc], val);
            }
        }
}

// ---------------------------------------------------------------------------
// 8-phase 256x256 MFMA GEMM (frozen since R8; uv GEMM).
template <int KT, int EPI, typename TO>
__global__ __launch_bounds__(512, 2) void k_mgemm8(const bf16* __restrict__ A, int lda,
                                                   const bf16* __restrict__ Bt,
                                                   const float* __restrict__ bias,
                                                   TO* __restrict__ out, int ldo,
                                                   int nb /* N/256 */) {
    constexpr int K = KT * 64;
    __shared__ __align__(16) char lds[131072];

    const int tid = threadIdx.x;
    const int lane = tid & 63;
    const int wid = tid >> 6;
    const int wr = wid >> 2;
    const int wc = wid & 3;

    int wgid = blockIdx.x;
    if ((gridDim.x & 7) == 0) {
        int cpx = gridDim.x >> 3;
        wgid = (wgid & 7) * cpx + (wgid >> 3);
    }
    const int m0 = (wgid / nb) * 256;
    const int n0 = (wgid % nb) * 256;

    auto ldsA = [&](int d, int kh) -> char* { return (char*)lds + d * 32768 + kh * 16384; };
    auto ldsB = [&](int d, int kh) -> char* { return (char*)lds + 65536 + d * 32768 + kh * 16384; };

    auto stage = [&](int op, int kh, int tt) {
        char* base = op ? ldsB(tt & 1, kh) : ldsA(tt & 1, kh);
        const bf16* g = op ? Bt : A;
        const int rowbase = op ? n0 : m0;
        const int ldr = op ? K : lda;
        #pragma unroll
        for (int l = 0; l < 2; ++l) {
            int q = tid + l * 512;
            int r = q >> 2;
            int cl = (q & 3) ^ ((r ^ (r >> 2)) & 3);
            const bf16* src = g + (size_t)(rowbase + r) * ldr + tt * 64 + kh * 32 + cl * 8;
            gload_lds16(src, (bf16*)(base + q * 16));
        }
    };
    auto rdA = [&](int d, int ks, int mi) -> bf16x8 {
        int row = wr * 128 + mi * 16 + (lane & 15);
        int ch = (lane >> 4) ^ ((row ^ (row >> 2)) & 3);
        return *(const bf16x8*)(ldsA(d, ks) + row * 64 + ch * 16);
    };
    auto rdB = [&](int d, int ks, int nj) -> bf16x8 {
        int row = wc * 64 + nj * 16 + (lane & 15);
        int ch = (lane >> 4) ^ ((row ^ (row >> 2)) & 3);
        return *(const bf16x8*)(ldsB(d, ks) + row * 64 + ch * 16);
    };

    f32x4 acc[8][4] = {};
    bf16x8 aF[4], bF[4];

    stage(0, 0, 0); stage(1, 0, 0); stage(0, 1, 0); stage(1, 1, 0);
    stage(0, 0, 1); stage(1, 0, 1);
    VMCNT(8);
    __builtin_amdgcn_s_barrier();
    __builtin_amdgcn_sched_barrier(0);

    #pragma unroll
    for (int t = 0; t < KT; ++t) {
        const int d = t & 1;
        #pragma unroll
        for (int mi = 0; mi < 4; ++mi) aF[mi] = rdA(d, 0, mi);
        #pragma unroll
        for (int nj = 0; nj < 4; ++nj) bF[nj] = rdB(d, 0, nj);
        if (t + 1 < KT) stage(0, 1, t + 1);
        __builtin_amdgcn_s_barrier();
        __builtin_amdgcn_s_setprio(1);
        #pragma unroll
        for (int mi = 0; mi < 4; ++mi)
            #pragma unroll
            for (int nj = 0; nj < 4; ++nj)
                acc[mi][nj] = __builtin_amdgcn_mfma_f32_16x16x32_bf16(aF[mi], bF[nj], acc[mi][nj], 0, 0, 0);
        __builtin_amdgcn_s_setprio(0);
        __builtin_amdgcn_s_barrier();
        #pragma unroll
        for (int mi = 0; mi < 4; ++mi) aF[mi] = rdA(d, 0, mi + 4);
        if (t + 1 < KT) stage(1, 1, t + 1);
        if (t + 1 < KT) { VMCNT(8); } else { VMCNT(0); }
        __builtin_amdgcn_s_barrier();
        __builtin_amdgcn_sched_barrier(0);
        __builtin_amdgcn_s_setprio(1);
        #pragma unroll
        for (int mi = 0; mi < 4; ++mi)
            #pragma unroll
            for (int nj = 0; nj < 4; ++nj)
                acc[mi + 4][nj] = __builtin_amdgcn_mfma_f32_16x16x32_bf16(aF[mi], bF[nj], acc[mi + 4][nj], 0, 0, 0);
        __builtin_amdgcn_s_setprio(0);
        __builtin_amdgcn_s_barrier();
        #pragma unroll
        for (int mi = 0; mi < 4; ++mi) aF[mi] = rdA(d, 1, mi);
        #pragma unroll
        for (int nj = 0; nj < 4; ++nj) bF[nj] = rdB(d, 1, nj);
        if (t + 2 < KT) stage(0, 0, t + 2);
        __builtin_amdgcn_s_barrier();
        __builtin_amdgcn_s_setprio(1);
        #pragma unroll
        for (int mi = 0; mi < 4; ++mi)
            #pragma unroll
            for (int nj = 0; nj < 4; ++nj)
                acc[mi][nj] = __builtin_amdgcn_mfma_f32_16x16x32_bf16(aF[mi], bF[nj], acc[mi][nj], 0, 0, 0);
        __builtin_amdgcn_s_setprio(0);
        __builtin_amdgcn_s_barrier();
        #pragma unroll
        for (int mi = 0; mi < 4; ++mi) aF[mi] = rdA(d, 1, mi + 4);
        if (t + 2 < KT) stage(1, 0, t + 2);
        if (t + 2 < KT)      { VMCNT(8); }
        else if (t + 1 < KT) { VMCNT(4); }
        __builtin_amdgcn_s_barrier();
        __builtin_amdgcn_sched_barrier(0);
        __builtin_amdgcn_s_setprio(1);
        #pragma unroll
        for (int mi = 0; mi < 4; ++mi)
            #pragma unroll
            for (int nj = 0; nj < 4; ++nj)
                acc[mi + 4][nj] = __builtin_amdgcn_mfma_f32_16x16x32_bf16(aF[mi], bF[nj], acc[mi + 4][nj], 0, 0, 0);
        __builtin_amdgcn_s_setprio(0);
        __builtin_amdgcn_s_barrier();
    }

    const int crow = (lane >> 4) * 4;
    const int ccol = lane & 15;
    #pragma unroll
    for (int mi = 0; mi < 8; ++mi)
        #pragma unroll
        for (int nj = 0; nj < 4; ++nj) {
            int gc = n0 + wc * 64 + nj * 16 + ccol;
            float bb = bias[gc];
            #pragma unroll
            for (int r = 0; r < 4; ++r) {
                int gr = m0 + wr * 128 + mi * 16 + crow + r;
                float val = acc[mi][nj][r] + bb;
                if (EPI == 1) val = val / (1.0f + expf(-val));
                stf(&out[(size_t)gr * ldo + gc], val);
            }
        }
}

// ---------------------------------------------------------------------------
// v channel transpose: Vt[c][b][ij(pad 224)] = v[b*196+ij][c]
__global__ __launch_bounds__(256) void k_vt(const bf16* __restrict__ uv,
                                            bf16* __restrict__ Vt) {
    const int c0 = blockIdx.x * 64;
    const int b  = blockIdx.y;
    const int tid = threadIdx.x;
    __shared__ bf16 t[196][66];
    for (int f = tid; f < 196 * 64; f += 256) {
        int ij = f >> 6, cl = f & 63;
        t[ij][cl] = uv[((size_t)b * 196 + ij) * 2048 + 1024 + c0 + cl];
    }
    __syncthreads();
    const bf16 z = __float2bfloat16(0.0f);
    for (int f = tid; f < 64 * 224; f += 256) {
        int cl = f / 224, ij = f - cl * 224;
        Vt[((size_t)(c0 + cl) * 64 + b) * 224 + ij] = (ij < 196) ? t[ij][cl] : z;
    }
}

// ---------------------------------------------------------------------------
// Per-channel Toeplitz GEMM, both halves via blockIdx.z.
__global__ __launch_bounds__(256) void k_convm(const bf16* __restrict__ Ab,
                                               const bf16* __restrict__ Vt,
                                               bf16* __restrict__ Yt) {
    __shared__ __align__(16) bf16 Ts[112 * 232];
    __shared__ bf16 As[736];
    const int mh = blockIdx.x;
    const int cl = blockIdx.y;
    const int c = (int)blockIdx.z * 512 + cl;
    const int tid = threadIdx.x;
    const int mbase = mh * 112;

    for (int e = tid; e < 729; e += 256)
        As[e] = Ab[(size_t)e * 1024 + c];
    __syncthreads();

    const bf16 z = __float2bfloat16(0.0f);
    if (tid < 224) {
        const int i = tid / 14, j = tid - i * 14;
        const bool kvalid = tid < 196;
        int p = mbase / 14, q = 0;
        for (int r = 0; r < 112; ++r) {
            bf16 val = z;
            if (kvalid && (mbase + r) < 196)
                val = As[(p - i + 13) * 27 + (q - j + 13)];
            Ts[r * 232 + tid] = val;
            if (++q == 14) { q = 0; ++p; }
        }
    }
    __syncthreads();

    const int lane = tid & 63;
    const int w = tid >> 6;
    const int lr = lane & 15;
    const int lk = (lane >> 4) * 8;
    const bf16* Vc = Vt + (size_t)c * 64 * 224;

    bf16x8 bfr[7];
    #pragma unroll
    for (int ks = 0; ks < 7; ++ks)
        bfr[ks] = *(const bf16x8*)&Vc[(size_t)(w * 16 + lr) * 224 + ks * 32 + lk];

    f32x4 acc[7] = {};
    #pragma unroll
    for (int ks = 0; ks < 7; ++ks)
        #pragma unroll
        for (int mi = 0; mi < 7; ++mi) {
            bf16x8 a = *(const bf16x8*)&Ts[(mi * 16 + lr) * 232 + ks * 32 + lk];
            acc[mi] = __builtin_amdgcn_mfma_f32_16x16x32_bf16(a, bfr[ks], acc[mi], 0, 0, 0);
        }

    const int crow = (lane >> 4) * 4;
    const int bb = w * 16 + (lane & 15);
    #pragma unroll
    for (int mi = 0; mi < 7; ++mi) {
        int pq = mbase + mi * 16 + crow;
        #pragma unroll
        for (int r = 0; r < 4; ++r)
            if (pq + r < 196)
                Yt[((size_t)c * 196 + pq + r) * 64 + bb] = __float2bfloat16(acc[mi][r]);
    }
}

// ---------------------------------------------------------------------------
__global__ __launch_bounds__(256) void k_gate(bf16* __restrict__ uv,
                                              const bf16* __restrict__ Yt) {
    const int pq = blockIdx.x;
    const int ct = blockIdx.y;
    const int cb = (int)blockIdx.z * 512;
    const int tid = threadIdx.x;
    __shared__ float t[64][65];
    for (int f = tid; f < 64 * 64; f += 256) {
        int cr = f >> 6, bcol = f & 63;
        t[cr][bcol] = __bfloat162float(Yt[((size_t)(cb + ct * 64 + cr) * 196 + pq) * 64 + bcol]);
    }
    __syncthreads();
    for (int f = tid; f < 64 * 64; f += 256) {
        int br = f >> 6, cc = f & 63;
        size_t row = (size_t)br * 196 + pq;
        int cglob = cb + ct * 64 + cc;
        float uu = __bfloat162float(uv[row * 2048 + cglob]);
        uv[row * 2048 + 1024 + cglob] = __float2bfloat16(t[cc][br] * uu);
    }
}

// ---------------------------------------------------------------------------
extern "C" void kernel_launch(void* const* d_in, const int* in_sizes, int n_in,
                              void* d_out, int out_size, void* d_ws, size_t ws_size,
                              hipStream_t stream) {
    const float* x    = (const float*)d_in[0];
    const float* Wu   = (const float*)d_in[3];
    const float* bu   = (const float*)d_in[4];
    const float* Wv   = (const float*)d_in[5];
    const float* bv   = (const float*)d_in[6];
    const float* Wo   = (const float*)d_in[7];
    const float* bo   = (const float*)d_in[8];
    const float* rpw  = (const float*)d_in[9];
    const float* rpb  = (const float*)d_in[10];
    const float* w1   = (const float*)d_in[11];
    const float* b1   = (const float*)d_in[12];
    const float* w2   = (const float*)d_in[13];
    const float* b2   = (const float*)d_in[14];
    const float* w3   = (const float*)d_in[15];
    const float* b3   = (const float*)d_in[16];
    const float* wOut = (const float*)d_in[17];
    const float* bOut = (const float*)d_in[18];

    char* ws = (char*)d_ws;
    size_t off = 0;
    auto take = [&](size_t bytes) { char* p = ws + off; off += (bytes + 255) & ~size_t(255); return p; };
    int*   bar    = (int*)take(64);
    bf16*  rnA    = (bf16*)take((size_t)768 * 512 * 2);
    bf16*  rnB    = (bf16*)take((size_t)768 * 512 * 2);
    float* p1     = (float*)take((size_t)768 * 8 * 4);
    float* p2     = (float*)take((size_t)768 * 8 * 4);
    float* p3     = (float*)take((size_t)768 * 8 * 4);
    bf16*  Ab     = (bf16*)take((size_t)RPOS * 1024 * 2);
    bf16*  xb     = (bf16*)take((size_t)ROWS * EE * 2);
    bf16*  WuvT   = (bf16*)take((size_t)2048 * 512 * 2);
    bf16*  WoT    = (bf16*)take((size_t)512 * 1024 * 2);
    bf16*  w1T    = (bf16*)take((size_t)512 * 512 * 2);
    bf16*  w2T    = (bf16*)take((size_t)512 * 512 * 2);
    bf16*  w3T    = (bf16*)take((size_t)512 * 512 * 2);
    bf16*  wOutT  = (bf16*)take((size_t)1024 * 512 * 2);
    float* biasUv = (float*)take(2048 * 4);
    bf16*  uvb    = (bf16*)take((size_t)ROWS * 2048 * 2);
    bf16*  Vt     = (bf16*)take((size_t)1024 * 64 * 224 * 2);
    bf16*  Yt     = (bf16*)take((size_t)1024 * 196 * 64 * 2);

    // Zero barrier counters (deterministic per launch; capture-legal).
    hipMemsetAsync(bar, 0, 64, stream);

    // --- all prep in one dispatch ---
    k_prep<<<9096, 256, 0, stream>>>(Wu, Wv, Wo, w1, w2, w3, wOut, bu, bv, x,
                                     WuvT, WoT, w1T, w2T, w3T, wOutT, biasUv, xb);

    // --- RPE MLP: one persistent dispatch ---
    k_rpe_all<<<192, 256, 0, stream>>>(rpw, rpb, w1T, b1, w2T, b2, w3T, b3,
                                       wOutT, bOut, rnA, rnB, p1, p2, p3, Ab, bar);

    // --- uv = silu(x @ [Wu|Wv] + [bu|bv])  (8-phase 256^2, KT=8) ---
    k_mgemm8<8, 1, bf16><<<392, 512, 0, stream>>>(xb, 512, WuvT, biasUv, uvb, 2048, 8);

    // --- v -> channel-major Vt ---
    k_vt<<<dim3(16, 64), 256, 0, stream>>>(uvb, Vt);

    // --- Toeplitz conv (MFMA) + gating ---
    k_convm<<<dim3(2, 512, 2), 256, 0, stream>>>(Ab, Vt, Yt);
    k_gate<<<dim3(196, 8, 2), 256, 0, stream>>>(uvb, Yt);

    // --- out = g @ Wo + bo  (m97 128^2, grid 392) ---
    k_mgemm<0, float><<<dim3(4, 98), 256, 0, stream>>>(uvb + 1024, 2048, WoT, bo,
                                                       (float*)d_out, 512, ROWS, 512, 1024);
}

// Round 13
// 239.112 us; speedup vs baseline: 1.4332x; 1.4332x over previous
//
#include <hip/hip_runtime.h>
#include <hip/hip_bf16.h>

typedef __hip_bfloat16 bf16;
typedef __attribute__((ext_vector_type(8))) short bf16x8;
typedef __attribute__((ext_vector_type(4))) float f32x4;

constexpr int NB    = 64;
constexpr int EE    = 512;
constexpr int RPOS  = 27 * 27;       // 729
constexpr int ROWS  = NB * 14 * 14;  // 12544

#define RMS_EPS 1e-6f
#define GAMMA_LOG2 (-0.00144344319f)   // log2(0.999)

__device__ __forceinline__ void  stf(float* p, float v) { *p = v; }
__device__ __forceinline__ void  stf(bf16* p, float v)  { *p = __float2bfloat16(v); }

__device__ __forceinline__ void gload_lds16(const bf16* g, bf16* l) {
    __builtin_amdgcn_global_load_lds(
        (const __attribute__((address_space(1))) void*)g,
        (__attribute__((address_space(3))) void*)l, 16, 0, 0);
}

#define VMCNT(n) asm volatile("s_waitcnt vmcnt(" #n ")" ::: "memory")

// ---------------------------------------------------------------------------
// One-shot prep: 7 weight transposes, bias concat, x -> bf16, Vt pad-zero.
__global__ __launch_bounds__(256) void k_prep(const float* __restrict__ Wu,
                                              const float* __restrict__ Wv,
                                              const float* __restrict__ Wo,
                                              const float* __restrict__ w1,
                                              const float* __restrict__ w2,
                                              const float* __restrict__ w3,
                                              const float* __restrict__ wOut,
                                              const float* __restrict__ bu,
                                              const float* __restrict__ bv,
                                              const float* __restrict__ x,
                                              bf16* __restrict__ WuvT,
                                              bf16* __restrict__ WoT,
                                              bf16* __restrict__ w1T,
                                              bf16* __restrict__ w2T,
                                              bf16* __restrict__ w3T,
                                              bf16* __restrict__ wOutT,
                                              float* __restrict__ biasUv,
                                              bf16* __restrict__ xb,
                                              bf16* __restrict__ Vt) {
    __shared__ float t[32][33];
    const int tid = threadIdx.x;
    int b = blockIdx.x;

    const float* src = nullptr; bf16* dst = nullptr; int R = 0, C = 0, nbx = 0;
    if (b < 512)        { src = Wu;   dst = WuvT;                      R = 512;  C = 1024; nbx = 32; }
    else if (b < 1024)  { b -= 512;   src = Wv; dst = WuvT + (size_t)1024 * 512; R = 512; C = 1024; nbx = 32; }
    else if (b < 1536)  { b -= 1024;  src = Wo;   dst = WoT;           R = 1024; C = 512;  nbx = 16; }
    else if (b < 1792)  { b -= 1536;  src = w1;   dst = w1T;           R = 512;  C = 512;  nbx = 16; }
    else if (b < 2048)  { b -= 1792;  src = w2;   dst = w2T;           R = 512;  C = 512;  nbx = 16; }
    else if (b < 2304)  { b -= 2048;  src = w3;   dst = w3T;           R = 512;  C = 512;  nbx = 16; }
    else if (b < 2816)  { b -= 2304;  src = wOut; dst = wOutT;         R = 512;  C = 1024; nbx = 32; }
    else if (b < 2824) {               // bias concat
        int c = (b - 2816) * 256 + tid;
        if (c < 2048) biasUv[c] = (c < 1024) ? bu[c] : bv[c - 1024];
        return;
    } else if (b < 9096) {             // x -> bf16
        int i = (b - 2824) * 256 + tid;
        float4 v = *(const float4*)&x[(size_t)i * 4];
        bf16* d = &xb[(size_t)i * 4];
        d[0] = __float2bfloat16(v.x);
        d[1] = __float2bfloat16(v.y);
        d[2] = __float2bfloat16(v.z);
        d[3] = __float2bfloat16(v.w);
        return;
    } else {                           // Vt pad-zero: 1024 blocks, ij 196..223
        int c = b - 9096;
        const bf16 z = __float2bfloat16(0.0f);
        for (int f = tid; f < 64 * 28; f += 256) {
            int bb = f / 28, k = f - bb * 28;
            Vt[((size_t)c * 64 + bb) * 224 + 196 + k] = z;
        }
        return;
    }
    int bx = (b % nbx) * 32;
    int by = (b / nbx) * 32;
    int tx = tid & 31, ty = tid >> 5;
    #pragma unroll
    for (int i = 0; i < 4; ++i)
        t[ty + i * 8][tx] = src[(size_t)(by + ty + i * 8) * C + bx + tx];
    __syncthreads();
    #pragma unroll
    for (int i = 0; i < 4; ++i)
        dst[(size_t)(bx + ty + i * 8) * R + by + tx] = __float2bfloat16(t[tx][ty + i * 8]);
}

// ---------------------------------------------------------------------------
// fused: r0 = ii*w0 + jj*w1 + b;  out = bf16(relu(rms_norm(r0)))
__global__ void k_rpe_pos_norm(const float* __restrict__ w, const float* __restrict__ bias,
                               bf16* __restrict__ out) {
    int p = blockIdx.x;
    float ii = (float)(p / 27 - 13);
    float jj = (float)(p % 27 - 13);
    int c0 = threadIdx.x, c1 = threadIdx.x + 256;
    float v0 = ii * w[c0] + jj * w[512 + c0] + bias[c0];
    float v1 = ii * w[c1] + jj * w[512 + c1] + bias[c1];
    float s = v0 * v0 + v1 * v1;
    #pragma unroll
    for (int off = 32; off; off >>= 1) s += __shfl_down(s, off, 64);
    __shared__ float ps[4];
    if ((threadIdx.x & 63) == 0) ps[threadIdx.x >> 6] = s;
    __syncthreads();
    float tot = ps[0] + ps[1] + ps[2] + ps[3];
    float scale = rsqrtf(tot * (1.0f / 512.0f) + RMS_EPS);
    out[(size_t)p * 512 + c0] = __float2bfloat16(fmaxf(v0 * scale, 0.0f));
    out[(size_t)p * 512 + c1] = __float2bfloat16(fmaxf(v1 * scale, 0.0f));
}

// ---------------------------------------------------------------------------
// RPE-layer GEMM with fused norm bookkeeping (64x64 tile, BK=32, 4 waves).
// Identity: relu(rmsnorm(x)) @ W = s_row * (relu(x) @ W), s_row > 0.
template <int SCALE_IN, int EPI>
__global__ __launch_bounds__(256) void k_rpe_gemm(const bf16* __restrict__ A,
                                                  const bf16* __restrict__ Bt,
                                                  const float* __restrict__ bias,
                                                  const float* __restrict__ pIn,
                                                  float* __restrict__ pOut,
                                                  bf16* __restrict__ out,
                                                  int M, int N, int K) {
    __shared__ bf16 As[64 * 32];
    __shared__ bf16 Bs[64 * 32];
    const int tid = threadIdx.x;
    const int m0 = blockIdx.y * 64;
    const int n0 = blockIdx.x * 64;
    const int lane = tid & 63;
    const int w = tid >> 6;
    const int lr = lane & 15;
    const int lk = (lane >> 4) * 8;

    f32x4 acc[4] = {};
    const int row = tid >> 2;
    const int seg = (tid & 3) * 8;

    for (int k0 = 0; k0 < K; k0 += 32) {
        gload_lds16(&A[(size_t)(m0 + row) * K + k0 + seg], &As[tid * 8]);
        gload_lds16(&Bt[(size_t)(n0 + row) * K + k0 + seg], &Bs[tid * 8]);
        __syncthreads();
        bf16x8 af = *(const bf16x8*)&As[(w * 16 + lr) * 32 + lk];
        #pragma unroll
        for (int j = 0; j < 4; ++j) {
            bf16x8 bf = *(const bf16x8*)&Bs[(j * 16 + lr) * 32 + lk];
            acc[j] = __builtin_amdgcn_mfma_f32_16x16x32_bf16(af, bf, acc[j], 0, 0, 0);
        }
        __syncthreads();
    }

    const int crow = (lane >> 4) * 4;
    const int ccol = lane & 15;
    float sc[4];
    #pragma unroll
    for (int r = 0; r < 4; ++r) {
        sc[r] = 1.0f;
        if (SCALE_IN) {
            int gr = m0 + w * 16 + crow + r;
            if (gr < M) {
                const float* pp = &pIn[(size_t)gr * 8];
                float s8 = pp[0] + pp[1] + pp[2] + pp[3] + pp[4] + pp[5] + pp[6] + pp[7];
                sc[r] = rsqrtf(s8 * (1.0f / 512.0f) + RMS_EPS);
            }
        }
    }
    float rowsq[4] = {0.f, 0.f, 0.f, 0.f};
    #pragma unroll
    for (int j = 0; j < 4; ++j) {
        int gc = n0 + j * 16 + ccol;
        float bb = bias[gc];
        #pragma unroll
        for (int r = 0; r < 4; ++r) {
            int gr = m0 + w * 16 + crow + r;
            float val = acc[j][r] * sc[r] + bb;
            if (EPI == 0) {
                rowsq[r] += val * val;
                if (gr < M) out[(size_t)gr * N + gc] = __float2bfloat16(fmaxf(val, 0.0f));
            } else {
                if (gr < M) {
                    int i = gr / 27, jj = gr % 27;
                    float decay = exp2f((float)(abs(i - 13) + abs(jj - 13)) * GAMMA_LOG2);
                    out[(size_t)gr * N + gc] = __float2bfloat16(val * decay);
                }
            }
        }
    }
    if (EPI == 0) {
        #pragma unroll
        for (int r = 0; r < 4; ++r) {
            #pragma unroll
            for (int m = 1; m < 16; m <<= 1) rowsq[r] += __shfl_xor(rowsq[r], m, 64);
        }
        if ((lane & 15) == 0) {
            #pragma unroll
            for (int r = 0; r < 4; ++r) {
                int gr = m0 + w * 16 + crow + r;
                if (gr < M) pOut[(size_t)gr * 8 + blockIdx.x] = rowsq[r];
            }
        }
    }
}

// ---------------------------------------------------------------------------
// m97-structure 128x128 MFMA GEMM (out GEMM; ~3 blocks/CU).
template <int EPI, typename TO>
__global__ __launch_bounds__(256) void k_mgemm(const bf16* __restrict__ A, int lda,
                                               const bf16* __restrict__ Bt,
                                               const float* __restrict__ bias,
                                               TO* __restrict__ out, int ldo,
                                               int M, int N, int K) {
    __shared__ bf16 As[128 * 32];
    __shared__ bf16 Bs[128 * 32];
    const int tid = threadIdx.x;
    const int m0 = blockIdx.y * 128;
    const int n0 = blockIdx.x * 128;
    const int lane = tid & 63;
    const int w = tid >> 6;
    const int wr = (w >> 1) * 64;
    const int wc = (w & 1) * 64;
    const int lr = lane & 15;
    const int lk = (lane >> 4) * 8;

    f32x4 acc[4][4] = {};

    for (int k0 = 0; k0 < K; k0 += 32) {
        #pragma unroll
        for (int t = 0; t < 2; ++t) {
            int flat = t * 256 + tid;
            int row = flat >> 2;
            int seg = (flat & 3) * 8;
            gload_lds16(&A[(size_t)(m0 + row) * lda + k0 + seg], &As[flat * 8]);
            gload_lds16(&Bt[(size_t)(n0 + row) * K + k0 + seg], &Bs[flat * 8]);
        }
        __syncthreads();
        bf16x8 af[4], bf[4];
        #pragma unroll
        for (int i = 0; i < 4; ++i) {
            af[i] = *(const bf16x8*)&As[(wr + i * 16 + lr) * 32 + lk];
            bf[i] = *(const bf16x8*)&Bs[(wc + i * 16 + lr) * 32 + lk];
        }
        #pragma unroll
        for (int i = 0; i < 4; ++i)
            #pragma unroll
            for (int j = 0; j < 4; ++j)
                acc[i][j] = __builtin_amdgcn_mfma_f32_16x16x32_bf16(af[i], bf[j], acc[i][j], 0, 0, 0);
        __syncthreads();
    }

    const int crow = (lane >> 4) * 4;
    const int ccol = lane & 15;
    #pragma unroll
    for (int i = 0; i < 4; ++i)
        #pragma unroll
        for (int j = 0; j < 4; ++j) {
            int gc = n0 + wc + j * 16 + ccol;
            float bb = bias[gc];
            #pragma unroll
            for (int r = 0; r < 4; ++r) {
                int gr = m0 + wr + i * 16 + crow + r;
                float val = acc[i][j][r] + bb;
                if (EPI == 1) val = val / (1.0f + expf(-val));
                stf(&out[(size_t)gr * ldo + gc], val);
            }
        }
}

// ---------------------------------------------------------------------------
// 8-phase 256x256 MFMA GEMM (schedule frozen since R8; uv GEMM).
// EPI==1 epilogue: silu; u-half (gc<1024) -> out row-major; v-half -> Vt
// channel-major [c][b][ij pad 224] (replaces the k_vt transpose pass).
template <int KT, int EPI, typename TO>
__global__ __launch_bounds__(512, 2) void k_mgemm8(const bf16* __restrict__ A, int lda,
                                                   const bf16* __restrict__ Bt,
                                                   const float* __restrict__ bias,
                                                   TO* __restrict__ out, int ldo,
                                                   int nb /* N/256 */,
                                                   bf16* __restrict__ Vt) {
    constexpr int K = KT * 64;
    __shared__ __align__(16) char lds[131072];

    const int tid = threadIdx.x;
    const int lane = tid & 63;
    const int wid = tid >> 6;
    const int wr = wid >> 2;
    const int wc = wid & 3;

    int wgid = blockIdx.x;
    if ((gridDim.x & 7) == 0) {
        int cpx = gridDim.x >> 3;
        wgid = (wgid & 7) * cpx + (wgid >> 3);
    }
    const int m0 = (wgid / nb) * 256;
    const int n0 = (wgid % nb) * 256;

    auto ldsA = [&](int d, int kh) -> char* { return (char*)lds + d * 32768 + kh * 16384; };
    auto ldsB = [&](int d, int kh) -> char* { return (char*)lds + 65536 + d * 32768 + kh * 16384; };

    auto stage = [&](int op, int kh, int tt) {
        char* base = op ? ldsB(tt & 1, kh) : ldsA(tt & 1, kh);
        const bf16* g = op ? Bt : A;
        const int rowbase = op ? n0 : m0;
        const int ldr = op ? K : lda;
        #pragma unroll
        for (int l = 0; l < 2; ++l) {
            int q = tid + l * 512;
            int r = q >> 2;
            int cl = (q & 3) ^ ((r ^ (r >> 2)) & 3);
            const bf16* src = g + (size_t)(rowbase + r) * ldr + tt * 64 + kh * 32 + cl * 8;
            gload_lds16(src, (bf16*)(base + q * 16));
        }
    };
    auto rdA = [&](int d, int ks, int mi) -> bf16x8 {
        int row = wr * 128 + mi * 16 + (lane & 15);
        int ch = (lane >> 4) ^ ((row ^ (row >> 2)) & 3);
        return *(const bf16x8*)(ldsA(d, ks) + row * 64 + ch * 16);
    };
    auto rdB = [&](int d, int ks, int nj) -> bf16x8 {
        int row = wc * 64 + nj * 16 + (lane & 15);
        int ch = (lane >> 4) ^ ((row ^ (row >> 2)) & 3);
        return *(const bf16x8*)(ldsB(d, ks) + row * 64 + ch * 16);
    };

    f32x4 acc[8][4] = {};
    bf16x8 aF[4], bF[4];

    stage(0, 0, 0); stage(1, 0, 0); stage(0, 1, 0); stage(1, 1, 0);
    stage(0, 0, 1); stage(1, 0, 1);
    VMCNT(8);
    __builtin_amdgcn_s_barrier();
    __builtin_amdgcn_sched_barrier(0);

    #pragma unroll
    for (int t = 0; t < KT; ++t) {
        const int d = t & 1;
        #pragma unroll
        for (int mi = 0; mi < 4; ++mi) aF[mi] = rdA(d, 0, mi);
        #pragma unroll
        for (int nj = 0; nj < 4; ++nj) bF[nj] = rdB(d, 0, nj);
        if (t + 1 < KT) stage(0, 1, t + 1);
        __builtin_amdgcn_s_barrier();
        __builtin_amdgcn_s_setprio(1);
        #pragma unroll
        for (int mi = 0; mi < 4; ++mi)
            #pragma unroll
            for (int nj = 0; nj < 4; ++nj)
                acc[mi][nj] = __builtin_amdgcn_mfma_f32_16x16x32_bf16(aF[mi], bF[nj], acc[mi][nj], 0, 0, 0);
        __builtin_amdgcn_s_setprio(0);
        __builtin_amdgcn_s_barrier();
        #pragma unroll
        for (int mi = 0; mi < 4; ++mi) aF[mi] = rdA(d, 0, mi + 4);
        if (t + 1 < KT) stage(1, 1, t + 1);
        if (t + 1 < KT) { VMCNT(8); } else { VMCNT(0); }
        __builtin_amdgcn_s_barrier();
        __builtin_amdgcn_sched_barrier(0);
        __builtin_amdgcn_s_setprio(1);
        #pragma unroll
        for (int mi = 0; mi < 4; ++mi)
            #pragma unroll
            for (int nj = 0; nj < 4; ++nj)
                acc[mi + 4][nj] = __builtin_amdgcn_mfma_f32_16x16x32_bf16(aF[mi], bF[nj], acc[mi + 4][nj], 0, 0, 0);
        __builtin_amdgcn_s_setprio(0);
        __builtin_amdgcn_s_barrier();
        #pragma unroll
        for (int mi = 0; mi < 4; ++mi) aF[mi] = rdA(d, 1, mi);
        #pragma unroll
        for (int nj = 0; nj < 4; ++nj) bF[nj] = rdB(d, 1, nj);
        if (t + 2 < KT) stage(0, 0, t + 2);
        __builtin_amdgcn_s_barrier();
        __builtin_amdgcn_s_setprio(1);
        #pragma unroll
        for (int mi = 0; mi < 4; ++mi)
            #pragma unroll
            for (int nj = 0; nj < 4; ++nj)
                acc[mi][nj] = __builtin_amdgcn_mfma_f32_16x16x32_bf16(aF[mi], bF[nj], acc[mi][nj], 0, 0, 0);
        __builtin_amdgcn_s_setprio(0);
        __builtin_amdgcn_s_barrier();
        #pragma unroll
        for (int mi = 0; mi < 4; ++mi) aF[mi] = rdA(d, 1, mi + 4);
        if (t + 2 < KT) stage(1, 0, t + 2);
        if (t + 2 < KT)      { VMCNT(8); }
        else if (t + 1 < KT) { VMCNT(4); }
        __builtin_amdgcn_s_barrier();
        __builtin_amdgcn_sched_barrier(0);
        __builtin_amdgcn_s_setprio(1);
        #pragma unroll
        for (int mi = 0; mi < 4; ++mi)
            #pragma unroll
            for (int nj = 0; nj < 4; ++nj)
                acc[mi + 4][nj] = __builtin_amdgcn_mfma_f32_16x16x32_bf16(aF[mi], bF[nj], acc[mi + 4][nj], 0, 0, 0);
        __builtin_amdgcn_s_setprio(0);
        __builtin_amdgcn_s_barrier();
    }

    const int crow = (lane >> 4) * 4;
    const int ccol = lane & 15;
    #pragma unroll
    for (int mi = 0; mi < 8; ++mi)
        #pragma unroll
        for (int nj = 0; nj < 4; ++nj) {
            int gc = n0 + wc * 64 + nj * 16 + ccol;
            float bb = bias[gc];
            #pragma unroll
            for (int r = 0; r < 4; ++r) {
                int gr = m0 + wr * 128 + mi * 16 + crow + r;
                float val = acc[mi][nj][r] + bb;
                if (EPI == 1) {
                    val = val / (1.0f + expf(-val));
                    if (gc < 1024) {
                        stf(&out[(size_t)gr * ldo + gc], val);
                    } else {
                        int c = gc - 1024;
                        int b = gr / 196;
                        int ij = gr - b * 196;
                        Vt[((size_t)c * 64 + b) * 224 + ij] = __float2bfloat16(val);
                    }
                } else {
                    stf(&out[(size_t)gr * ldo + gc], val);
                }
            }
        }
}

// ---------------------------------------------------------------------------
// Per-channel Toeplitz GEMM, both halves via blockIdx.z.
__global__ __launch_bounds__(256) void k_convm(const bf16* __restrict__ Ab,
                                               const bf16* __restrict__ Vt,
                                               bf16* __restrict__ Yt) {
    __shared__ __align__(16) bf16 Ts[112 * 232];
    __shared__ bf16 As[736];
    const int mh = blockIdx.x;
    const int cl = blockIdx.y;
    const int c = (int)blockIdx.z * 512 + cl;
    const int tid = threadIdx.x;
    const int mbase = mh * 112;

    for (int e = tid; e < 729; e += 256)
        As[e] = Ab[(size_t)e * 1024 + c];
    __syncthreads();

    const bf16 z = __float2bfloat16(0.0f);
    if (tid < 224) {
        const int i = tid / 14, j = tid - i * 14;
        const bool kvalid = tid < 196;
        int p = mbase / 14, q = 0;
        for (int r = 0; r < 112; ++r) {
            bf16 val = z;
            if (kvalid && (mbase + r) < 196)
                val = As[(p - i + 13) * 27 + (q - j + 13)];
            Ts[r * 232 + tid] = val;
            if (++q == 14) { q = 0; ++p; }
        }
    }
    __syncthreads();

    const int lane = tid & 63;
    const int w = tid >> 6;
    const int lr = lane & 15;
    const int lk = (lane >> 4) * 8;
    const bf16* Vc = Vt + (size_t)c * 64 * 224;

    bf16x8 bfr[7];
    #pragma unroll
    for (int ks = 0; ks < 7; ++ks)
        bfr[ks] = *(const bf16x8*)&Vc[(size_t)(w * 16 + lr) * 224 + ks * 32 + lk];

    f32x4 acc[7] = {};
    #pragma unroll
    for (int ks = 0; ks < 7; ++ks)
        #pragma unroll
        for (int mi = 0; mi < 7; ++mi) {
            bf16x8 a = *(const bf16x8*)&Ts[(mi * 16 + lr) * 232 + ks * 32 + lk];
            acc[mi] = __builtin_amdgcn_mfma_f32_16x16x32_bf16(a, bfr[ks], acc[mi], 0, 0, 0);
        }

    const int crow = (lane >> 4) * 4;
    const int bb = w * 16 + (lane & 15);
    #pragma unroll
    for (int mi = 0; mi < 7; ++mi) {
        int pq = mbase + mi * 16 + crow;
        #pragma unroll
        for (int r = 0; r < 4; ++r)
            if (pq + r < 196)
                Yt[((size_t)c * 196 + pq + r) * 64 + bb] = __float2bfloat16(acc[mi][r]);
    }
}

// ---------------------------------------------------------------------------
__global__ __launch_bounds__(256) void k_gate(bf16* __restrict__ uv,
                                              const bf16* __restrict__ Yt) {
    const int pq = blockIdx.x;
    const int ct = blockIdx.y;
    const int cb = (int)blockIdx.z * 512;
    const int tid = threadIdx.x;
    __shared__ float t[64][65];
    for (int f = tid; f < 64 * 64; f += 256) {
        int cr = f >> 6, bcol = f & 63;
        t[cr][bcol] = __bfloat162float(Yt[((size_t)(cb + ct * 64 + cr) * 196 + pq) * 64 + bcol]);
    }
    __syncthreads();
    for (int f = tid; f < 64 * 64; f += 256) {
        int br = f >> 6, cc = f & 63;
        size_t row = (size_t)br * 196 + pq;
        int cglob = cb + ct * 64 + cc;
        float uu = __bfloat162float(uv[row * 2048 + cglob]);
        uv[row * 2048 + 1024 + cglob] = __float2bfloat16(t[cc][br] * uu);
    }
}

// ---------------------------------------------------------------------------
extern "C" void kernel_launch(void* const* d_in, const int* in_sizes, int n_in,
                              void* d_out, int out_size, void* d_ws, size_t ws_size,
                              hipStream_t stream) {
    const float* x    = (const float*)d_in[0];
    const float* Wu   = (const float*)d_in[3];
    const float* bu   = (const float*)d_in[4];
    const float* Wv   = (const float*)d_in[5];
    const float* bv   = (const float*)d_in[6];
    const float* Wo   = (const float*)d_in[7];
    const float* bo   = (const float*)d_in[8];
    const float* rpw  = (const float*)d_in[9];
    const float* rpb  = (const float*)d_in[10];
    const float* w1   = (const float*)d_in[11];
    const float* b1   = (const float*)d_in[12];
    const float* w2   = (const float*)d_in[13];
    const float* b2   = (const float*)d_in[14];
    const float* w3   = (const float*)d_in[15];
    const float* b3   = (const float*)d_in[16];
    const float* wOut = (const float*)d_in[17];
    const float* bOut = (const float*)d_in[18];

    char* ws = (char*)d_ws;
    size_t off = 0;
    auto take = [&](size_t bytes) { char* p = ws + off; off += (bytes + 255) & ~size_t(255); return p; };
    bf16*  rnA    = (bf16*)take((size_t)768 * 512 * 2);
    bf16*  rnB    = (bf16*)take((size_t)768 * 512 * 2);
    float* p1     = (float*)take((size_t)768 * 8 * 4);
    float* p2     = (float*)take((size_t)768 * 8 * 4);
    float* p3     = (float*)take((size_t)768 * 8 * 4);
    bf16*  Ab     = (bf16*)take((size_t)RPOS * 1024 * 2);
    bf16*  xb     = (bf16*)take((size_t)ROWS * EE * 2);
    bf16*  WuvT   = (bf16*)take((size_t)2048 * 512 * 2);
    bf16*  WoT    = (bf16*)take((size_t)512 * 1024 * 2);
    bf16*  w1T    = (bf16*)take((size_t)512 * 512 * 2);
    bf16*  w2T    = (bf16*)take((size_t)512 * 512 * 2);
    bf16*  w3T    = (bf16*)take((size_t)512 * 512 * 2);
    bf16*  wOutT  = (bf16*)take((size_t)1024 * 512 * 2);
    float* biasUv = (float*)take(2048 * 4);
    bf16*  uvb    = (bf16*)take((size_t)ROWS * 2048 * 2);
    bf16*  Vt     = (bf16*)take((size_t)1024 * 64 * 224 * 2);
    bf16*  Yt     = (bf16*)take((size_t)1024 * 196 * 64 * 2);

    // --- all prep (incl. Vt pad-zero) in one dispatch ---
    k_prep<<<10120, 256, 0, stream>>>(Wu, Wv, Wo, w1, w2, w3, wOut, bu, bv, x,
                                      WuvT, WoT, w1T, w2T, w3T, wOutT, biasUv, xb, Vt);

    // --- RPE MLP: pos+norm, then 4 GEMMs with fused norm bookkeeping ---
    k_rpe_pos_norm<<<RPOS, 256, 0, stream>>>(rpw, rpb, rnA);
    k_rpe_gemm<0, 0><<<dim3(8, 12), 256, 0, stream>>>(rnA, w1T, b1, nullptr, p1, rnB, RPOS, 512, 512);
    k_rpe_gemm<1, 0><<<dim3(8, 12), 256, 0, stream>>>(rnB, w2T, b2, p1, p2, rnA, RPOS, 512, 512);
    k_rpe_gemm<1, 0><<<dim3(8, 12), 256, 0, stream>>>(rnA, w3T, b3, p2, p3, rnB, RPOS, 512, 512);
    k_rpe_gemm<1, 2><<<dim3(16, 12), 256, 0, stream>>>(rnB, wOutT, bOut, p3, nullptr, Ab, RPOS, 1024, 512);

    // --- uv GEMM: u -> uvb, v -> Vt (channel-major) directly ---
    k_mgemm8<8, 1, bf16><<<392, 512, 0, stream>>>(xb, 512, WuvT, biasUv, uvb, 2048, 8, Vt);

    // --- Toeplitz conv (MFMA) + gating ---
    k_convm<<<dim3(2, 512, 2), 256, 0, stream>>>(Ab, Vt, Yt);
    k_gate<<<dim3(196, 8, 2), 256, 0, stream>>>(uvb, Yt);

    // --- out = g @ Wo + bo  (m97 128^2, grid 392) ---
    k_mgemm<0, float><<<dim3(4, 98), 256, 0, stream>>>(uvb + 1024, 2048, WoT, bo,
                                                       (float*)d_out, 512, ROWS, 512, 1024);
}

// Round 14
// 216.598 us; speedup vs baseline: 1.5822x; 1.1039x over previous
//
#include <hip/hip_runtime.h>
#include <hip/hip_bf16.h>

typedef __hip_bfloat16 bf16;
typedef __attribute__((ext_vector_type(8))) short bf16x8;
typedef __attribute__((ext_vector_type(4))) float f32x4;

constexpr int NB    = 64;
constexpr int EE    = 512;
constexpr int RPOS  = 27 * 27;       // 729
constexpr int ROWS  = NB * 14 * 14;  // 12544

#define RMS_EPS 1e-6f
#define GAMMA_LOG2 (-0.00144344319f)   // log2(0.999)

__device__ __forceinline__ void  stf(float* p, float v) { *p = v; }
__device__ __forceinline__ void  stf(bf16* p, float v)  { *p = __float2bfloat16(v); }

__device__ __forceinline__ void gload_lds16(const bf16* g, bf16* l) {
    __builtin_amdgcn_global_load_lds(
        (const __attribute__((address_space(1))) void*)g,
        (__attribute__((address_space(3))) void*)l, 16, 0, 0);
}

#define VMCNT(n) asm volatile("s_waitcnt vmcnt(" #n ")" ::: "memory")

// ---------------------------------------------------------------------------
// One-shot prep: 7 weight transposes (fp32 [R][C] -> bf16 [C][R]), bias
// concat, x -> bf16, AND the RPE pos+norm (independent of everything else).
__global__ __launch_bounds__(256) void k_prep(const float* __restrict__ Wu,
                                              const float* __restrict__ Wv,
                                              const float* __restrict__ Wo,
                                              const float* __restrict__ w1,
                                              const float* __restrict__ w2,
                                              const float* __restrict__ w3,
                                              const float* __restrict__ wOut,
                                              const float* __restrict__ bu,
                                              const float* __restrict__ bv,
                                              const float* __restrict__ x,
                                              const float* __restrict__ rpw,
                                              const float* __restrict__ rpb,
                                              bf16* __restrict__ WuvT,
                                              bf16* __restrict__ WoT,
                                              bf16* __restrict__ w1T,
                                              bf16* __restrict__ w2T,
                                              bf16* __restrict__ w3T,
                                              bf16* __restrict__ wOutT,
                                              float* __restrict__ biasUv,
                                              bf16* __restrict__ xb,
                                              bf16* __restrict__ rnA) {
    __shared__ float t[32][33];
    __shared__ float ps[4];
    const int tid = threadIdx.x;
    int b = blockIdx.x;

    const float* src = nullptr; bf16* dst = nullptr; int R = 0, C = 0, nbx = 0;
    if (b < 512)        { src = Wu;   dst = WuvT;                      R = 512;  C = 1024; nbx = 32; }
    else if (b < 1024)  { b -= 512;   src = Wv; dst = WuvT + (size_t)1024 * 512; R = 512; C = 1024; nbx = 32; }
    else if (b < 1536)  { b -= 1024;  src = Wo;   dst = WoT;           R = 1024; C = 512;  nbx = 16; }
    else if (b < 1792)  { b -= 1536;  src = w1;   dst = w1T;           R = 512;  C = 512;  nbx = 16; }
    else if (b < 2048)  { b -= 1792;  src = w2;   dst = w2T;           R = 512;  C = 512;  nbx = 16; }
    else if (b < 2304)  { b -= 2048;  src = w3;   dst = w3T;           R = 512;  C = 512;  nbx = 16; }
    else if (b < 2816)  { b -= 2304;  src = wOut; dst = wOutT;         R = 512;  C = 1024; nbx = 32; }
    else if (b < 2824) {               // bias concat
        int c = (b - 2816) * 256 + tid;
        if (c < 2048) biasUv[c] = (c < 1024) ? bu[c] : bv[c - 1024];
        return;
    } else if (b < 9096) {             // x -> bf16
        int i = (b - 2824) * 256 + tid;
        float4 v = *(const float4*)&x[(size_t)i * 4];
        bf16* d = &xb[(size_t)i * 4];
        d[0] = __float2bfloat16(v.x);
        d[1] = __float2bfloat16(v.y);
        d[2] = __float2bfloat16(v.z);
        d[3] = __float2bfloat16(v.w);
        return;
    } else {                           // RPE pos + rmsnorm + relu: 729 blocks
        int p = b - 9096;
        float ii = (float)(p / 27 - 13);
        float jj = (float)(p % 27 - 13);
        int c0 = tid, c1 = tid + 256;
        float v0 = ii * rpw[c0] + jj * rpw[512 + c0] + rpb[c0];
        float v1 = ii * rpw[c1] + jj * rpw[512 + c1] + rpb[c1];
        float s = v0 * v0 + v1 * v1;
        #pragma unroll
        for (int off = 32; off; off >>= 1) s += __shfl_down(s, off, 64);
        if ((tid & 63) == 0) ps[tid >> 6] = s;
        __syncthreads();
        float tot = ps[0] + ps[1] + ps[2] + ps[3];
        float scale = rsqrtf(tot * (1.0f / 512.0f) + RMS_EPS);
        rnA[(size_t)p * 512 + c0] = __float2bfloat16(fmaxf(v0 * scale, 0.0f));
        rnA[(size_t)p * 512 + c1] = __float2bfloat16(fmaxf(v1 * scale, 0.0f));
        return;
    }
    int bx = (b % nbx) * 32;
    int by = (b / nbx) * 32;
    int tx = tid & 31, ty = tid >> 5;
    #pragma unroll
    for (int i = 0; i < 4; ++i)
        t[ty + i * 8][tx] = src[(size_t)(by + ty + i * 8) * C + bx + tx];
    __syncthreads();
    #pragma unroll
    for (int i = 0; i < 4; ++i)
        dst[(size_t)(bx + ty + i * 8) * R + by + tx] = __float2bfloat16(t[tx][ty + i * 8]);
}

// ---------------------------------------------------------------------------
// RPE-layer GEMM with fused norm bookkeeping (64x64 tile, BK=32, 4 waves).
// Identity: relu(rmsnorm(x)) @ W = s_row * (relu(x) @ W), s_row > 0.
template <int SCALE_IN, int EPI>
__global__ __launch_bounds__(256) void k_rpe_gemm(const bf16* __restrict__ A,
                                                  const bf16* __restrict__ Bt,
                                                  const float* __restrict__ bias,
                                                  const float* __restrict__ pIn,
                                                  float* __restrict__ pOut,
                                                  bf16* __restrict__ out,
                                                  int M, int N, int K) {
    __shared__ bf16 As[64 * 32];
    __shared__ bf16 Bs[64 * 32];
    const int tid = threadIdx.x;
    const int m0 = blockIdx.y * 64;
    const int n0 = blockIdx.x * 64;
    const int lane = tid & 63;
    const int w = tid >> 6;
    const int lr = lane & 15;
    const int lk = (lane >> 4) * 8;

    f32x4 acc[4] = {};
    const int row = tid >> 2;
    const int seg = (tid & 3) * 8;

    for (int k0 = 0; k0 < K; k0 += 32) {
        gload_lds16(&A[(size_t)(m0 + row) * K + k0 + seg], &As[tid * 8]);
        gload_lds16(&Bt[(size_t)(n0 + row) * K + k0 + seg], &Bs[tid * 8]);
        __syncthreads();
        bf16x8 af = *(const bf16x8*)&As[(w * 16 + lr) * 32 + lk];
        #pragma unroll
        for (int j = 0; j < 4; ++j) {
            bf16x8 bf = *(const bf16x8*)&Bs[(j * 16 + lr) * 32 + lk];
            acc[j] = __builtin_amdgcn_mfma_f32_16x16x32_bf16(af, bf, acc[j], 0, 0, 0);
        }
        __syncthreads();
    }

    const int crow = (lane >> 4) * 4;
    const int ccol = lane & 15;
    float sc[4];
    #pragma unroll
    for (int r = 0; r < 4; ++r) {
        sc[r] = 1.0f;
        if (SCALE_IN) {
            int gr = m0 + w * 16 + crow + r;
            if (gr < M) {
                const float* pp = &pIn[(size_t)gr * 8];
                float s8 = pp[0] + pp[1] + pp[2] + pp[3] + pp[4] + pp[5] + pp[6] + pp[7];
                sc[r] = rsqrtf(s8 * (1.0f / 512.0f) + RMS_EPS);
            }
        }
    }
    float rowsq[4] = {0.f, 0.f, 0.f, 0.f};
    #pragma unroll
    for (int j = 0; j < 4; ++j) {
        int gc = n0 + j * 16 + ccol;
        float bb = bias[gc];
        #pragma unroll
        for (int r = 0; r < 4; ++r) {
            int gr = m0 + w * 16 + crow + r;
            float val = acc[j][r] * sc[r] + bb;
            if (EPI == 0) {
                rowsq[r] += val * val;
                if (gr < M) out[(size_t)gr * N + gc] = __float2bfloat16(fmaxf(val, 0.0f));
            } else {
                if (gr < M) {
                    int i = gr / 27, jj = gr % 27;
                    float decay = exp2f((float)(abs(i - 13) + abs(jj - 13)) * GAMMA_LOG2);
                    out[(size_t)gr * N + gc] = __float2bfloat16(val * decay);
                }
            }
        }
    }
    if (EPI == 0) {
        #pragma unroll
        for (int r = 0; r < 4; ++r) {
            #pragma unroll
            for (int m = 1; m < 16; m <<= 1) rowsq[r] += __shfl_xor(rowsq[r], m, 64);
        }
        if ((lane & 15) == 0) {
            #pragma unroll
            for (int r = 0; r < 4; ++r) {
                int gr = m0 + w * 16 + crow + r;
                if (gr < M) pOut[(size_t)gr * 8 + blockIdx.x] = rowsq[r];
            }
        }
    }
}

// ---------------------------------------------------------------------------
// m97-structure 128x128 MFMA GEMM (out GEMM; ~3 blocks/CU).
template <int EPI, typename TO>
__global__ __launch_bounds__(256) void k_mgemm(const bf16* __restrict__ A, int lda,
                                               const bf16* __restrict__ Bt,
                                               const float* __restrict__ bias,
                                               TO* __restrict__ out, int ldo,
                                               int M, int N, int K) {
    __shared__ bf16 As[128 * 32];
    __shared__ bf16 Bs[128 * 32];
    const int tid = threadIdx.x;
    const int m0 = blockIdx.y * 128;
    const int n0 = blockIdx.x * 128;
    const int lane = tid & 63;
    const int w = tid >> 6;
    const int wr = (w >> 1) * 64;
    const int wc = (w & 1) * 64;
    const int lr = lane & 15;
    const int lk = (lane >> 4) * 8;

    f32x4 acc[4][4] = {};

    for (int k0 = 0; k0 < K; k0 += 32) {
        #pragma unroll
        for (int t = 0; t < 2; ++t) {
            int flat = t * 256 + tid;
            int row = flat >> 2;
            int seg = (flat & 3) * 8;
            gload_lds16(&A[(size_t)(m0 + row) * lda + k0 + seg], &As[flat * 8]);
            gload_lds16(&Bt[(size_t)(n0 + row) * K + k0 + seg], &Bs[flat * 8]);
        }
        __syncthreads();
        bf16x8 af[4], bf[4];
        #pragma unroll
        for (int i = 0; i < 4; ++i) {
            af[i] = *(const bf16x8*)&As[(wr + i * 16 + lr) * 32 + lk];
            bf[i] = *(const bf16x8*)&Bs[(wc + i * 16 + lr) * 32 + lk];
        }
        #pragma unroll
        for (int i = 0; i < 4; ++i)
            #pragma unroll
            for (int j = 0; j < 4; ++j)
                acc[i][j] = __builtin_amdgcn_mfma_f32_16x16x32_bf16(af[i], bf[j], acc[i][j], 0, 0, 0);
        __syncthreads();
    }

    const int crow = (lane >> 4) * 4;
    const int ccol = lane & 15;
    #pragma unroll
    for (int i = 0; i < 4; ++i)
        #pragma unroll
        for (int j = 0; j < 4; ++j) {
            int gc = n0 + wc + j * 16 + ccol;
            float bb = bias[gc];
            #pragma unroll
            for (int r = 0; r < 4; ++r) {
                int gr = m0 + wr + i * 16 + crow + r;
                float val = acc[i][j][r] + bb;
                if (EPI == 1) val = val / (1.0f + expf(-val));
                stf(&out[(size_t)gr * ldo + gc], val);
            }
        }
}

// ---------------------------------------------------------------------------
// 8-phase 256x256 MFMA GEMM (schedule frozen since R8; uv GEMM).
template <int KT, int EPI, typename TO>
__global__ __launch_bounds__(512, 2) void k_mgemm8(const bf16* __restrict__ A, int lda,
                                                   const bf16* __restrict__ Bt,
                                                   const float* __restrict__ bias,
                                                   TO* __restrict__ out, int ldo,
                                                   int nb /* N/256 */) {
    constexpr int K = KT * 64;
    __shared__ __align__(16) char lds[131072];

    const int tid = threadIdx.x;
    const int lane = tid & 63;
    const int wid = tid >> 6;
    const int wr = wid >> 2;
    const int wc = wid & 3;

    int wgid = blockIdx.x;
    if ((gridDim.x & 7) == 0) {
        int cpx = gridDim.x >> 3;
        wgid = (wgid & 7) * cpx + (wgid >> 3);
    }
    const int m0 = (wgid / nb) * 256;
    const int n0 = (wgid % nb) * 256;

    auto ldsA = [&](int d, int kh) -> char* { return (char*)lds + d * 32768 + kh * 16384; };
    auto ldsB = [&](int d, int kh) -> char* { return (char*)lds + 65536 + d * 32768 + kh * 16384; };

    auto stage = [&](int op, int kh, int tt) {
        char* base = op ? ldsB(tt & 1, kh) : ldsA(tt & 1, kh);
        const bf16* g = op ? Bt : A;
        const int rowbase = op ? n0 : m0;
        const int ldr = op ? K : lda;
        #pragma unroll
        for (int l = 0; l < 2; ++l) {
            int q = tid + l * 512;
            int r = q >> 2;
            int cl = (q & 3) ^ ((r ^ (r >> 2)) & 3);
            const bf16* src = g + (size_t)(rowbase + r) * ldr + tt * 64 + kh * 32 + cl * 8;
            gload_lds16(src, (bf16*)(base + q * 16));
        }
    };
    auto rdA = [&](int d, int ks, int mi) -> bf16x8 {
        int row = wr * 128 + mi * 16 + (lane & 15);
        int ch = (lane >> 4) ^ ((row ^ (row >> 2)) & 3);
        return *(const bf16x8*)(ldsA(d, ks) + row * 64 + ch * 16);
    };
    auto rdB = [&](int d, int ks, int nj) -> bf16x8 {
        int row = wc * 64 + nj * 16 + (lane & 15);
        int ch = (lane >> 4) ^ ((row ^ (row >> 2)) & 3);
        return *(const bf16x8*)(ldsB(d, ks) + row * 64 + ch * 16);
    };

    f32x4 acc[8][4] = {};
    bf16x8 aF[4], bF[4];

    stage(0, 0, 0); stage(1, 0, 0); stage(0, 1, 0); stage(1, 1, 0);
    stage(0, 0, 1); stage(1, 0, 1);
    VMCNT(8);
    __builtin_amdgcn_s_barrier();
    __builtin_amdgcn_sched_barrier(0);

    #pragma unroll
    for (int t = 0; t < KT; ++t) {
        const int d = t & 1;
        #pragma unroll
        for (int mi = 0; mi < 4; ++mi) aF[mi] = rdA(d, 0, mi);
        #pragma unroll
        for (int nj = 0; nj < 4; ++nj) bF[nj] = rdB(d, 0, nj);
        if (t + 1 < KT) stage(0, 1, t + 1);
        __builtin_amdgcn_s_barrier();
        __builtin_amdgcn_s_setprio(1);
        #pragma unroll
        for (int mi = 0; mi < 4; ++mi)
            #pragma unroll
            for (int nj = 0; nj < 4; ++nj)
                acc[mi][nj] = __builtin_amdgcn_mfma_f32_16x16x32_bf16(aF[mi], bF[nj], acc[mi][nj], 0, 0, 0);
        __builtin_amdgcn_s_setprio(0);
        __builtin_amdgcn_s_barrier();
        #pragma unroll
        for (int mi = 0; mi < 4; ++mi) aF[mi] = rdA(d, 0, mi + 4);
        if (t + 1 < KT) stage(1, 1, t + 1);
        if (t + 1 < KT) { VMCNT(8); } else { VMCNT(0); }
        __builtin_amdgcn_s_barrier();
        __builtin_amdgcn_sched_barrier(0);
        __builtin_amdgcn_s_setprio(1);
        #pragma unroll
        for (int mi = 0; mi < 4; ++mi)
            #pragma unroll
            for (int nj = 0; nj < 4; ++nj)
                acc[mi + 4][nj] = __builtin_amdgcn_mfma_f32_16x16x32_bf16(aF[mi], bF[nj], acc[mi + 4][nj], 0, 0, 0);
        __builtin_amdgcn_s_setprio(0);
        __builtin_amdgcn_s_barrier();
        #pragma unroll
        for (int mi = 0; mi < 4; ++mi) aF[mi] = rdA(d, 1, mi);
        #pragma unroll
        for (int nj = 0; nj < 4; ++nj) bF[nj] = rdB(d, 1, nj);
        if (t + 2 < KT) stage(0, 0, t + 2);
        __builtin_amdgcn_s_barrier();
        __builtin_amdgcn_s_setprio(1);
        #pragma unroll
        for (int mi = 0; mi < 4; ++mi)
            #pragma unroll
            for (int nj = 0; nj < 4; ++nj)
                acc[mi][nj] = __builtin_amdgcn_mfma_f32_16x16x32_bf16(aF[mi], bF[nj], acc[mi][nj], 0, 0, 0);
        __builtin_amdgcn_s_setprio(0);
        __builtin_amdgcn_s_barrier();
        #pragma unroll
        for (int mi = 0; mi < 4; ++mi) aF[mi] = rdA(d, 1, mi + 4);
        if (t + 2 < KT) stage(1, 0, t + 2);
        if (t + 2 < KT)      { VMCNT(8); }
        else if (t + 1 < KT) { VMCNT(4); }
        __builtin_amdgcn_s_barrier();
        __builtin_amdgcn_sched_barrier(0);
        __builtin_amdgcn_s_setprio(1);
        #pragma unroll
        for (int mi = 0; mi < 4; ++mi)
            #pragma unroll
            for (int nj = 0; nj < 4; ++nj)
                acc[mi + 4][nj] = __builtin_amdgcn_mfma_f32_16x16x32_bf16(aF[mi], bF[nj], acc[mi + 4][nj], 0, 0, 0);
        __builtin_amdgcn_s_setprio(0);
        __builtin_amdgcn_s_barrier();
    }

    const int crow = (lane >> 4) * 4;
    const int ccol = lane & 15;
    #pragma unroll
    for (int mi = 0; mi < 8; ++mi)
        #pragma unroll
        for (int nj = 0; nj < 4; ++nj) {
            int gc = n0 + wc * 64 + nj * 16 + ccol;
            float bb = bias[gc];
            #pragma unroll
            for (int r = 0; r < 4; ++r) {
                int gr = m0 + wr * 128 + mi * 16 + crow + r;
                float val = acc[mi][nj][r] + bb;
                if (EPI == 1) val = val / (1.0f + expf(-val));
                stf(&out[(size_t)gr * ldo + gc], val);
            }
        }
}

// ---------------------------------------------------------------------------
// v channel transpose: Vt[c][b][ij(pad 224)] = v[b*196+ij][c]
__global__ __launch_bounds__(256) void k_vt(const bf16* __restrict__ uv,
                                            bf16* __restrict__ Vt) {
    const int c0 = blockIdx.x * 64;
    const int b  = blockIdx.y;
    const int tid = threadIdx.x;
    __shared__ bf16 t[196][66];
    for (int f = tid; f < 196 * 64; f += 256) {
        int ij = f >> 6, cl = f & 63;
        t[ij][cl] = uv[((size_t)b * 196 + ij) * 2048 + 1024 + c0 + cl];
    }
    __syncthreads();
    const bf16 z = __float2bfloat16(0.0f);
    for (int f = tid; f < 64 * 224; f += 256) {
        int cl = f / 224, ij = f - cl * 224;
        Vt[((size_t)(c0 + cl) * 64 + b) * 224 + ij] = (ij < 196) ? t[ij][cl] : z;
    }
}

// ---------------------------------------------------------------------------
// Per-channel Toeplitz GEMM, both halves via blockIdx.z.
__global__ __launch_bounds__(256) void k_convm(const bf16* __restrict__ Ab,
                                               const bf16* __restrict__ Vt,
                                               bf16* __restrict__ Yt) {
    __shared__ __align__(16) bf16 Ts[112 * 232];
    __shared__ bf16 As[736];
    const int mh = blockIdx.x;
    const int cl = blockIdx.y;
    const int c = (int)blockIdx.z * 512 + cl;
    const int tid = threadIdx.x;
    const int mbase = mh * 112;

    for (int e = tid; e < 729; e += 256)
        As[e] = Ab[(size_t)e * 1024 + c];
    __syncthreads();

    const bf16 z = __float2bfloat16(0.0f);
    if (tid < 224) {
        const int i = tid / 14, j = tid - i * 14;
        const bool kvalid = tid < 196;
        int p = mbase / 14, q = 0;
        for (int r = 0; r < 112; ++r) {
            bf16 val = z;
            if (kvalid && (mbase + r) < 196)
                val = As[(p - i + 13) * 27 + (q - j + 13)];
            Ts[r * 232 + tid] = val;
            if (++q == 14) { q = 0; ++p; }
        }
    }
    __syncthreads();

    const int lane = tid & 63;
    const int w = tid >> 6;
    const int lr = lane & 15;
    const int lk = (lane >> 4) * 8;
    const bf16* Vc = Vt + (size_t)c * 64 * 224;

    bf16x8 bfr[7];
    #pragma unroll
    for (int ks = 0; ks < 7; ++ks)
        bfr[ks] = *(const bf16x8*)&Vc[(size_t)(w * 16 + lr) * 224 + ks * 32 + lk];

    f32x4 acc[7] = {};
    #pragma unroll
    for (int ks = 0; ks < 7; ++ks)
        #pragma unroll
        for (int mi = 0; mi < 7; ++mi) {
            bf16x8 a = *(const bf16x8*)&Ts[(mi * 16 + lr) * 232 + ks * 32 + lk];
            acc[mi] = __builtin_amdgcn_mfma_f32_16x16x32_bf16(a, bfr[ks], acc[mi], 0, 0, 0);
        }

    const int crow = (lane >> 4) * 4;
    const int bb = w * 16 + (lane & 15);
    #pragma unroll
    for (int mi = 0; mi < 7; ++mi) {
        int pq = mbase + mi * 16 + crow;
        #pragma unroll
        for (int r = 0; r < 4; ++r)
            if (pq + r < 196)
                Yt[((size_t)c * 196 + pq + r) * 64 + bb] = __float2bfloat16(acc[mi][r]);
    }
}

// ---------------------------------------------------------------------------
__global__ __launch_bounds__(256) void k_gate(bf16* __restrict__ uv,
                                              const bf16* __restrict__ Yt) {
    const int pq = blockIdx.x;
    const int ct = blockIdx.y;
    const int cb = (int)blockIdx.z * 512;
    const int tid = threadIdx.x;
    __shared__ float t[64][65];
    for (int f = tid; f < 64 * 64; f += 256) {
        int cr = f >> 6, bcol = f & 63;
        t[cr][bcol] = __bfloat162float(Yt[((size_t)(cb + ct * 64 + cr) * 196 + pq) * 64 + bcol]);
    }
    __syncthreads();
    for (int f = tid; f < 64 * 64; f += 256) {
        int br = f >> 6, cc = f & 63;
        size_t row = (size_t)br * 196 + pq;
        int cglob = cb + ct * 64 + cc;
        float uu = __bfloat162float(uv[row * 2048 + cglob]);
        uv[row * 2048 + 1024 + cglob] = __float2bfloat16(t[cc][br] * uu);
    }
}

// ---------------------------------------------------------------------------
extern "C" void kernel_launch(void* const* d_in, const int* in_sizes, int n_in,
                              void* d_out, int out_size, void* d_ws, size_t ws_size,
                              hipStream_t stream) {
    const float* x    = (const float*)d_in[0];
    const float* Wu   = (const float*)d_in[3];
    const float* bu   = (const float*)d_in[4];
    const float* Wv   = (const float*)d_in[5];
    const float* bv   = (const float*)d_in[6];
    const float* Wo   = (const float*)d_in[7];
    const float* bo   = (const float*)d_in[8];
    const float* rpw  = (const float*)d_in[9];
    const float* rpb  = (const float*)d_in[10];
    const float* w1   = (const float*)d_in[11];
    const float* b1   = (const float*)d_in[12];
    const float* w2   = (const float*)d_in[13];
    const float* b2   = (const float*)d_in[14];
    const float* w3   = (const float*)d_in[15];
    const float* b3   = (const float*)d_in[16];
    const float* wOut = (const float*)d_in[17];
    const float* bOut = (const float*)d_in[18];

    char* ws = (char*)d_ws;
    size_t off = 0;
    auto take = [&](size_t bytes) { char* p = ws + off; off += (bytes + 255) & ~size_t(255); return p; };
    bf16*  rnA    = (bf16*)take((size_t)768 * 512 * 2);
    bf16*  rnB    = (bf16*)take((size_t)768 * 512 * 2);
    float* p1     = (float*)take((size_t)768 * 8 * 4);
    float* p2     = (float*)take((size_t)768 * 8 * 4);
    float* p3     = (float*)take((size_t)768 * 8 * 4);
    bf16*  Ab     = (bf16*)take((size_t)RPOS * 1024 * 2);
    bf16*  xb     = (bf16*)take((size_t)ROWS * EE * 2);
    bf16*  WuvT   = (bf16*)take((size_t)2048 * 512 * 2);
    bf16*  WoT    = (bf16*)take((size_t)512 * 1024 * 2);
    bf16*  w1T    = (bf16*)take((size_t)512 * 512 * 2);
    bf16*  w2T    = (bf16*)take((size_t)512 * 512 * 2);
    bf16*  w3T    = (bf16*)take((size_t)512 * 512 * 2);
    bf16*  wOutT  = (bf16*)take((size_t)1024 * 512 * 2);
    float* biasUv = (float*)take(2048 * 4);
    bf16*  uvb    = (bf16*)take((size_t)ROWS * 2048 * 2);
    bf16*  Vt     = (bf16*)take((size_t)1024 * 64 * 224 * 2);
    bf16*  Yt     = (bf16*)take((size_t)1024 * 196 * 64 * 2);

    // --- all prep (incl. RPE pos+norm) in one dispatch ---
    k_prep<<<9825, 256, 0, stream>>>(Wu, Wv, Wo, w1, w2, w3, wOut, bu, bv, x,
                                     rpw, rpb,
                                     WuvT, WoT, w1T, w2T, w3T, wOutT, biasUv, xb, rnA);

    // --- RPE MLP: 4 GEMMs with fused norm bookkeeping ---
    k_rpe_gemm<0, 0><<<dim3(8, 12), 256, 0, stream>>>(rnA, w1T, b1, nullptr, p1, rnB, RPOS, 512, 512);
    k_rpe_gemm<1, 0><<<dim3(8, 12), 256, 0, stream>>>(rnB, w2T, b2, p1, p2, rnA, RPOS, 512, 512);
    k_rpe_gemm<1, 0><<<dim3(8, 12), 256, 0, stream>>>(rnA, w3T, b3, p2, p3, rnB, RPOS, 512, 512);
    k_rpe_gemm<1, 2><<<dim3(16, 12), 256, 0, stream>>>(rnB, wOutT, bOut, p3, nullptr, Ab, RPOS, 1024, 512);

    // --- uv = silu(x @ [Wu|Wv] + [bu|bv])  (8-phase 256^2, KT=8) ---
    k_mgemm8<8, 1, bf16><<<392, 512, 0, stream>>>(xb, 512, WuvT, biasUv, uvb, 2048, 8);

    // --- v -> channel-major Vt ---
    k_vt<<<dim3(16, 64), 256, 0, stream>>>(uvb, Vt);

    // --- Toeplitz conv (MFMA) + gating ---
    k_convm<<<dim3(2, 512, 2), 256, 0, stream>>>(Ab, Vt, Yt);
    k_gate<<<dim3(196, 8, 2), 256, 0, stream>>>(uvb, Yt);

    // --- out = g @ Wo + bo  (m97 128^2, grid 392) ---
    k_mgemm<0, float><<<dim3(4, 98), 256, 0, stream>>>(uvb + 1024, 2048, WoT, bo,
                                                       (float*)d_out, 512, ROWS, 512, 1024);
}